// Round 5
// baseline (145.671 us; speedup 1.0000x reference)
//
#include <hip/hip_runtime.h>
#include <math.h>
#include <stdint.h>

#define T_TOK 8192
#define NEXP  256
#define HD    7168
#define PLANE ((size_t)T_TOK * NEXP)
#define SCALE 4096.0f
#define INV_S2 (1.0f / 16777216.0f)   // 2^-24
#define BM 128
#define BN 128
#define BK 32                          // fp32 K-columns per step
#define NSTEP_TOT (HD / BK)            // 224
#define BIMG_STEP 32768                // bytes per K-step: 2 nb * 16 KB

typedef _Float16 h8  __attribute__((ext_vector_type(8)));
typedef float f32x16 __attribute__((ext_vector_type(16)));
typedef __attribute__((address_space(3))) uint8_t       lds_t;
typedef __attribute__((address_space(1))) const uint8_t gbl_t;

// ---- W -> pre-swizzled f16 hi/lo LDS image, [t][nb][hl][row(128)][slot(4)] ----
// chunk c (16 B) within step: nb=c>>10, hl=(c>>9)&1, row=(c>>2)&127, sp=c&3.
// content: plane hl of W[nb*128+row][t*32 + (sp ^ ((row>>1)&3))*8 .. +7] * SCALE.
__global__ __launch_bounds__(256) void wconv(const float* __restrict__ W,
                                             _Float16* __restrict__ img) {
  const int cc  = blockIdx.x * 256 + threadIdx.x;
  const int t   = cc >> 11;
  const int c   = cc & 2047;
  const int nb  = c >> 10;
  const int hl  = (c >> 9) & 1;
  const int row = (c >> 2) & 127;
  const int sp  = c & 3;
  const int sl  = sp ^ ((row >> 1) & 3);
  const int k   = t * BK + sl * 8;

  const float* src = W + (size_t)(nb * 128 + row) * HD + k;
  const float4 v0 = *(const float4*)src;
  const float4 v1 = *(const float4*)(src + 4);
  const float xs[8] = {v0.x, v0.y, v0.z, v0.w, v1.x, v1.y, v1.z, v1.w};
  h8 out;
#pragma unroll
  for (int j = 0; j < 8; ++j) {
    const float v = xs[j] * SCALE;
    const _Float16 hh = (_Float16)v;
    out[j] = hl ? (_Float16)(v - (float)hh) : hh;
  }
  *(h8*)(img + (size_t)cc * 8) = out;
}

// ---- Router GEMM: 128x128 tile, 4 waves of 64x64, 32x32x16 f16 MFMA, dual-acc 3-product ----
__global__ __launch_bounds__(256, 2) void router_gemm(
    const float* __restrict__ X, const _Float16* __restrict__ img,
    float* __restrict__ partial, int S) {
  __shared__ __align__(1024) _Float16 As[2][2][BM][BK];    // 32 KB
  __shared__ __align__(1024) _Float16 Bs[2][2][BN][BK];    // 32 KB

  const int tid = threadIdx.x;
  const int id  = blockIdx.x;
  // id = mb*(2S) + nb*S + sb : all mb for fixed (nb,sb) share one XCD (2S==8 at S=4)
  const int sb  = id % S;
  const int nb  = (id / S) & 1;
  const int mb  = id / (2 * S);

  const int row0  = mb * BM;
  const int nstep = (HD / S) / BK;
  const int tbase = sb * nstep;

  const int lane = tid & 63, wv = tid >> 6;
  const int wm = wv >> 1, wn = wv & 1;       // 4 waves: 2(M) x 2(N), each 64x64
  const int r31 = lane & 31, kg = lane >> 5;

  const int sm = tid >> 1;                   // staging row 0..127
  const int sk = tid & 1;                    // half-row selector (2 h8-slots each)

  const float* Ap = X + (size_t)(row0 + sm) * HD + tbase * BK + sk * 16;
  const uint8_t* imgB = (const uint8_t*)img + (size_t)tbase * BIMG_STEP + nb * 16384 + tid * 16;

  f32x16 accP[2][2], accQ[2][2];
#pragma unroll
  for (int i = 0; i < 2; ++i)
#pragma unroll
    for (int j = 0; j < 2; ++j) { accP[i][j] = (f32x16)(0.f); accQ[i][j] = (f32x16)(0.f); }

#define STAGE_B(t, b)                                                          \
  {                                                                            \
    const uint8_t* g = imgB + (size_t)(t) * BIMG_STEP;                         \
    uint8_t* l = (uint8_t*)&Bs[b][0][0][0] + tid * 16;                         \
    _Pragma("unroll")                                                          \
    for (int i = 0; i < 4; ++i)                                                \
      __builtin_amdgcn_global_load_lds((gbl_t*)(uintptr_t)(g + i * 4096),      \
                                       (lds_t*)(uintptr_t)(l + i * 4096),      \
                                       16, 0, 0);                              \
  }

#define CVT_WRITE(b, s, va, vb)                                                \
  {                                                                            \
    const float xs[8] = {va.x, va.y, va.z, va.w, vb.x, vb.y, vb.z, vb.w};      \
    h8 hv, lv_;                                                                \
    _Pragma("unroll")                                                          \
    for (int j = 0; j < 8; ++j) {                                              \
      const float v = xs[j] * SCALE;                                           \
      const _Float16 hh = (_Float16)v;                                         \
      hv[j] = hh; lv_[j] = (_Float16)(v - (float)hh);                          \
    }                                                                          \
    const int spp = (s) ^ ((sm >> 1) & 3);                                     \
    *(h8*)&As[b][0][sm][spp * 8] = hv;                                         \
    *(h8*)&As[b][1][sm][spp * 8] = lv_;                                        \
  }

  // prologue: stage step 0 into buf 0
  STAGE_B(0, 0);
  {
    const float4 a0 = *(const float4*)(Ap);
    const float4 a1 = *(const float4*)(Ap + 4);
    const float4 a2 = *(const float4*)(Ap + 8);
    const float4 a3 = *(const float4*)(Ap + 12);
    CVT_WRITE(0, sk * 2,     a0, a1);
    CVT_WRITE(0, sk * 2 + 1, a2, a3);
  }

  for (int t = 0; t < nstep; ++t) {
    const int cur = t & 1;
    __syncthreads();   // buf[cur] ready (compiler drains vmcnt/lgkm here)

    const bool more = (t + 1 < nstep);
    float4 a0, a1, a2, a3;
    if (more) {
      const float* ap = Ap + (size_t)(t + 1) * BK;
      a0 = *(const float4*)(ap);
      a1 = *(const float4*)(ap + 4);
      a2 = *(const float4*)(ap + 8);
      a3 = *(const float4*)(ap + 12);
      STAGE_B(t + 1, cur ^ 1);
    }

#pragma unroll
    for (int ks = 0; ks < 2; ++ks) {
      h8 aH[2], aL[2], bH[2], bL[2];
#pragma unroll
      for (int mi = 0; mi < 2; ++mi) {
        const int row = wm * 64 + mi * 32 + r31;
        const int sp  = (ks * 2 + kg) ^ ((row >> 1) & 3);
        aH[mi] = *(const h8*)&As[cur][0][row][sp * 8];
        aL[mi] = *(const h8*)&As[cur][1][row][sp * 8];
      }
#pragma unroll
      for (int ni = 0; ni < 2; ++ni) {
        const int col = wn * 64 + ni * 32 + r31;
        const int sp  = (ks * 2 + kg) ^ ((col >> 1) & 3);
        bH[ni] = *(const h8*)&Bs[cur][0][col][sp * 8];
        bL[ni] = *(const h8*)&Bs[cur][1][col][sp * 8];
      }
      __builtin_amdgcn_s_setprio(1);
      // P-wave: 4 independent; Q: 4 chains of 2 with issue distance 4
#pragma unroll
      for (int mi = 0; mi < 2; ++mi)
#pragma unroll
        for (int ni = 0; ni < 2; ++ni)
          accP[mi][ni] = __builtin_amdgcn_mfma_f32_32x32x16_f16(aH[mi], bH[ni], accP[mi][ni], 0, 0, 0);
#pragma unroll
      for (int mi = 0; mi < 2; ++mi)
#pragma unroll
        for (int ni = 0; ni < 2; ++ni)
          accQ[mi][ni] = __builtin_amdgcn_mfma_f32_32x32x16_f16(aL[mi], bH[ni], accQ[mi][ni], 0, 0, 0);
#pragma unroll
      for (int mi = 0; mi < 2; ++mi)
#pragma unroll
        for (int ni = 0; ni < 2; ++ni)
          accQ[mi][ni] = __builtin_amdgcn_mfma_f32_32x32x16_f16(aH[mi], bL[ni], accQ[mi][ni], 0, 0, 0);
      __builtin_amdgcn_s_setprio(0);
    }

    if (more) {  // convert + LDS-write late: HBM latency hidden under MFMA block
      const int nbuf = cur ^ 1;
      CVT_WRITE(nbuf, sk * 2,     a0, a1);
      CVT_WRITE(nbuf, sk * 2 + 1, a2, a3);
    }
  }

  // Epilogue. 32x32 C/D: col = lane&31, row = (reg&3) + 8*(reg>>2) + 4*(lane>>5)
  float* base = partial + (size_t)sb * PLANE;
#pragma unroll
  for (int mi = 0; mi < 2; ++mi)
#pragma unroll
    for (int ni = 0; ni < 2; ++ni) {
      const f32x16 acc = accP[mi][ni] + accQ[mi][ni];
      const int col = nb * BN + wn * 64 + ni * 32 + r31;
#pragma unroll
      for (int reg = 0; reg < 16; ++reg) {
        const int rr  = (reg & 3) + 8 * (reg >> 2) + 4 * kg;
        const int row = row0 + wm * 64 + mi * 32 + rr;
        base[(size_t)row * NEXP + col] = acc[reg];
      }
    }
}

// ---------------- Gating: one wave per token; sums S partial planes ----------------
__global__ __launch_bounds__(256) void gate_kernel(const float* __restrict__ logits,
                                                   const float* __restrict__ bias,
                                                   float* __restrict__ out_w,
                                                   float* __restrict__ out_e, int S) {
    const int wave = threadIdx.x >> 6;
    const int lane = threadIdx.x & 63;
    const int t = blockIdx.x * 4 + wave;
    if (t >= T_TOK) return;

    float l4[4] = {0.f, 0.f, 0.f, 0.f};
    for (int s = 0; s < S; ++s) {  // fixed order -> deterministic
        const float4 v = *(const float4*)(&logits[(size_t)s * PLANE + (size_t)t * NEXP + lane * 4]);
        l4[0] += v.x; l4[1] += v.y; l4[2] += v.z; l4[3] += v.w;
    }
    const float4 bv = *(const float4*)(&bias[lane * 4]);

    float s4[4], c[4];
#pragma unroll
    for (int j = 0; j < 4; ++j) s4[j] = 1.f / (1.f + expf(-l4[j] * INV_S2));
    c[0] = s4[0] + bv.x;
    c[1] = s4[1] + bv.y;
    c[2] = s4[2] + bv.z;
    c[3] = s4[3] + bv.w;

    float a = fmaxf(c[0], c[1]), b = fminf(c[0], c[1]);
    float d = fmaxf(c[2], c[3]), e = fminf(c[2], c[3]);
    float m1 = fmaxf(a, d);
    float m2 = fmaxf(fminf(a, d), fmaxf(b, e));
#pragma unroll
    for (int off = 1; off < 8; off <<= 1) {
        const float o1 = __shfl_xor(m1, off);
        const float o2 = __shfl_xor(m2, off);
        const float n1 = fmaxf(m1, o1);
        const float n2 = fmaxf(fminf(m1, o1), fmaxf(m2, o2));
        m1 = n1; m2 = n2;
    }
    const float gs = m1 + m2;
    const int   g  = lane >> 3;

    int rank = 0;
#pragma unroll
    for (int gg = 0; gg < 8; ++gg) {
        const float og = __shfl(gs, gg * 8);
        rank += (og > gs) || (og == gs && gg < g);
    }
    const bool gsel = rank < 4;

    float v[4];
#pragma unroll
    for (int j = 0; j < 4; ++j) v[j] = gsel ? c[j] : 0.0f;

    float selw = 0.f;
    int   seli = 0;
    float wsum = 0.f;

#pragma unroll
    for (int k = 0; k < 8; ++k) {
        float bvv = v[0]; int bi = lane * 4; float br = s4[0];
#pragma unroll
        for (int j = 1; j < 4; ++j) {
            if (v[j] > bvv) { bvv = v[j]; bi = lane * 4 + j; br = s4[j]; }
        }
#pragma unroll
        for (int off = 32; off > 0; off >>= 1) {
            const float ov = __shfl_xor(bvv, off);
            const int   oi = __shfl_xor(bi, off);
            const float orr = __shfl_xor(br, off);
            if (ov > bvv || (ov == bvv && oi < bi)) { bvv = ov; bi = oi; br = orr; }
        }
        if (lane == k) { selw = br; seli = bi; }
        wsum += br;
        const int rem = bi - lane * 4;
#pragma unroll
        for (int j = 0; j < 4; ++j)
            if (rem == j) v[j] = -INFINITY;
    }

    if (lane < 8) {
        const float w = selw / (wsum + 1e-20f) * 2.5f;
        out_w[(size_t)t * 8 + lane] = w;
        out_e[(size_t)t * 8 + lane] = (float)seli;
    }
}

extern "C" void kernel_launch(void* const* d_in, const int* in_sizes, int n_in,
                              void* d_out, int out_size, void* d_ws, size_t ws_size,
                              hipStream_t stream) {
    const float* X    = (const float*)d_in[0];
    const float* W    = (const float*)d_in[1];
    const float* bias = (const float*)d_in[2];
    float* out = (float*)d_out;

    _Float16* img = (_Float16*)d_ws;
    const size_t woff = (size_t)NSTEP_TOT * BIMG_STEP;   // 7,340,032 B
    float* partial = (float*)((char*)d_ws + woff);

    int S = 1;
    if (ws_size >= woff + 4 * PLANE * sizeof(float)) S = 4;
    else if (ws_size >= woff + 2 * PLANE * sizeof(float)) S = 2;

    wconv<<<dim3(NSTEP_TOT * 2048 / 256), 256, 0, stream>>>(W, img);
    router_gemm<<<dim3((T_TOK / BM) * 2 * S), 256, 0, stream>>>(X, img, partial, S);
    gate_kernel<<<dim3(T_TOK / 4), 256, 0, stream>>>(partial, bias, out, out + (size_t)T_TOK * 8, S);
}

// Round 6
// 131.212 us; speedup vs baseline: 1.1102x; 1.1102x over previous
//
#include <hip/hip_runtime.h>
#include <math.h>
#include <stdint.h>

#define T_TOK 8192
#define NEXP  256
#define HD    7168
#define PLANE ((size_t)T_TOK * NEXP)
#define SCALE 4096.0f
#define INV_S2 (1.0f / 16777216.0f)   // 2^-24
#define BM 128
#define BK 32                          // fp32 K-columns per step
#define NSTEP_TOT (HD / BK)            // 224
#define BIMG_STEP 32768                // bytes per K-step: 2 planes * 256 rows * 4 slots * 16B

typedef _Float16 h8  __attribute__((ext_vector_type(8)));
typedef float f32x16 __attribute__((ext_vector_type(16)));
typedef __attribute__((address_space(3))) uint8_t       lds_t;
typedef __attribute__((address_space(1))) const uint8_t gbl_t;

// ---- W -> pre-swizzled f16 hi/lo LDS image [t][hl][row(256)][slot(4)] (16B chunks) ----
// chunk c within step: hl=c>>10, row=(c&1023)>>2, sp=c&3.
// content: plane hl of W[row][t*32 + (sp ^ ((row>>1)&3))*8 .. +7] * SCALE.
__global__ __launch_bounds__(256) void wconv(const float* __restrict__ W,
                                             _Float16* __restrict__ img) {
  const int cc  = blockIdx.x * 256 + threadIdx.x;
  const int t   = cc >> 11;
  const int c   = cc & 2047;
  const int hl  = c >> 10;
  const int rem = c & 1023;
  const int row = rem >> 2;
  const int sp  = rem & 3;
  const int sl  = sp ^ ((row >> 1) & 3);
  const int k   = t * BK + sl * 8;

  const float* src = W + (size_t)row * HD + k;
  const float4 v0 = *(const float4*)src;
  const float4 v1 = *(const float4*)(src + 4);
  const float xs[8] = {v0.x, v0.y, v0.z, v0.w, v1.x, v1.y, v1.z, v1.w};
  h8 out;
#pragma unroll
  for (int j = 0; j < 8; ++j) {
    const float v = xs[j] * SCALE;
    const _Float16 hh = (_Float16)v;
    out[j] = hl ? (_Float16)(v - (float)hh) : hh;
  }
  *(h8*)(img + (size_t)cc * 8) = out;
}

// ---- Router GEMM: 128x256 tile, 8 waves of 64x64, counted-vmcnt pipeline (T3+T4) ----
__global__ __launch_bounds__(512, 2) void router_gemm(
    const float* __restrict__ X, const _Float16* __restrict__ img,
    float* __restrict__ partial, int S) {
  __shared__ __align__(1024) _Float16 As[2][2][BM][BK];    // 32 KB
  __shared__ __align__(1024) _Float16 Bs[2][2][NEXP][BK];  // 64 KB

  const int tid = threadIdx.x;
  const int id  = blockIdx.x;
  const int sb  = id % S;
  const int mb  = id / S;

  const int row0  = mb * BM;
  const int nstep = (HD / S) / BK;
  const int tbase = sb * nstep;

  const int lane = tid & 63, wv = tid >> 6;
  const int wm = wv >> 2, wn = wv & 3;       // 2(M) x 4(N) waves, 64x64 each
  const int r31 = lane & 31, kg = lane >> 5;

  const int sm = tid >> 2;                   // A staging row 0..127
  const int sk = tid & 3;                    // 8-float slot
  const int spA = sk ^ ((sm >> 1) & 3);

  const float* Ap = X + (size_t)(row0 + sm) * HD + tbase * BK + sk * 8;
  const uint8_t* imgB = (const uint8_t*)img + (size_t)tbase * BIMG_STEP + tid * 16;

  f32x16 accP[2][2], accQ[2][2];
#pragma unroll
  for (int i = 0; i < 2; ++i)
#pragma unroll
    for (int j = 0; j < 2; ++j) { accP[i][j] = (f32x16)(0.f); accQ[i][j] = (f32x16)(0.f); }

#define STAGE_B(t, b)                                                          \
  {                                                                            \
    const uint8_t* g = imgB + (size_t)(t) * BIMG_STEP;                         \
    uint8_t* l = (uint8_t*)&Bs[b][0][0][0] + tid * 16;                         \
    _Pragma("unroll")                                                          \
    for (int i = 0; i < 4; ++i)                                                \
      __builtin_amdgcn_global_load_lds((gbl_t*)(uintptr_t)(g + i * 8192),      \
                                       (lds_t*)(uintptr_t)(l + i * 8192),      \
                                       16, 0, 0);                              \
  }

#define CVT_WRITE_A(b, va, vb)                                                 \
  {                                                                            \
    const float xs[8] = {va.x, va.y, va.z, va.w, vb.x, vb.y, vb.z, vb.w};      \
    h8 hv, lv_;                                                                \
    _Pragma("unroll")                                                          \
    for (int j = 0; j < 8; ++j) {                                              \
      const float v = xs[j] * SCALE;                                           \
      const _Float16 hh = (_Float16)v;                                         \
      hv[j] = hh; lv_[j] = (_Float16)(v - (float)hh);                          \
    }                                                                          \
    *(h8*)&As[b][0][sm][spA * 8] = hv;                                         \
    *(h8*)&As[b][1][sm][spA * 8] = lv_;                                        \
  }

  // ---- prologue: fully stage step 0 into buf 0 ----
  {
    const float4 a0 = *(const float4*)(Ap);
    const float4 a1 = *(const float4*)(Ap + 4);
    __builtin_amdgcn_sched_barrier(0);
    STAGE_B(0, 0);
    asm volatile("s_waitcnt vmcnt(0)" ::: "memory");
    __builtin_amdgcn_sched_barrier(0);
    CVT_WRITE_A(0, a0, a1);
    asm volatile("s_waitcnt lgkmcnt(0)" ::: "memory");
    __builtin_amdgcn_s_barrier();
  }

  for (int t = 0; t < nstep; ++t) {
    const int cur = t & 1;
    const int nxt = cur ^ 1;
    const bool more = (t + 1 < nstep);

    float4 a0, a1;
    if (more) {
      const float* ap = Ap + (size_t)(t + 1) * BK;
      a0 = *(const float4*)(ap);          // A loads issued FIRST (oldest vmem)
      a1 = *(const float4*)(ap + 4);
      __builtin_amdgcn_sched_barrier(0);
      STAGE_B(t + 1, nxt);                // then 4 global_load_lds
      __builtin_amdgcn_sched_barrier(0);
      asm volatile("s_waitcnt vmcnt(6)" ::: "memory");   // oldest 4 (B-lds of step t) done
    } else {
      asm volatile("s_waitcnt vmcnt(0)" ::: "memory");
    }
    __builtin_amdgcn_sched_barrier(0);

    // read ALL 16 fragments for this step
    h8 aH[2][2], aL[2][2], bH[2][2], bL[2][2];
#pragma unroll
    for (int ks = 0; ks < 2; ++ks) {
#pragma unroll
      for (int mi = 0; mi < 2; ++mi) {
        const int row = wm * 64 + mi * 32 + r31;
        const int sp  = (ks * 2 + kg) ^ ((row >> 1) & 3);
        aH[ks][mi] = *(const h8*)&As[cur][0][row][sp * 8];
        aL[ks][mi] = *(const h8*)&As[cur][1][row][sp * 8];
      }
#pragma unroll
      for (int ni = 0; ni < 2; ++ni) {
        const int col = wn * 64 + ni * 32 + r31;
        const int sp  = (ks * 2 + kg) ^ ((col >> 1) & 3);
        bH[ks][ni] = *(const h8*)&Bs[cur][0][col][sp * 8];
        bL[ks][ni] = *(const h8*)&Bs[cur][1][col][sp * 8];
      }
    }
    asm volatile("s_waitcnt lgkmcnt(0)" ::: "memory");
    __builtin_amdgcn_sched_barrier(0);

    __builtin_amdgcn_s_setprio(1);
#pragma unroll
    for (int ks = 0; ks < 2; ++ks) {
#pragma unroll
      for (int mi = 0; mi < 2; ++mi)
#pragma unroll
        for (int ni = 0; ni < 2; ++ni)
          accP[mi][ni] = __builtin_amdgcn_mfma_f32_32x32x16_f16(aH[ks][mi], bH[ks][ni], accP[mi][ni], 0, 0, 0);
#pragma unroll
      for (int mi = 0; mi < 2; ++mi)
#pragma unroll
        for (int ni = 0; ni < 2; ++ni)
          accQ[mi][ni] = __builtin_amdgcn_mfma_f32_32x32x16_f16(aL[ks][mi], bH[ks][ni], accQ[mi][ni], 0, 0, 0);
#pragma unroll
      for (int mi = 0; mi < 2; ++mi)
#pragma unroll
        for (int ni = 0; ni < 2; ++ni)
          accQ[mi][ni] = __builtin_amdgcn_mfma_f32_32x32x16_f16(aH[ks][mi], bL[ks][ni], accQ[mi][ni], 0, 0, 0);
    }
    __builtin_amdgcn_s_setprio(0);

    if (more) {
      asm volatile("s_waitcnt vmcnt(4)" ::: "memory");   // A regs arrived; B-lds(t+1) stay in flight
      __builtin_amdgcn_sched_barrier(0);
      CVT_WRITE_A(nxt, a0, a1);
    }
    asm volatile("s_waitcnt lgkmcnt(0)" ::: "memory");   // my A-writes visible before barrier
    __builtin_amdgcn_s_barrier();
  }

  // Epilogue. 32x32 C/D: col = lane&31, row = (reg&3) + 8*(reg>>2) + 4*(lane>>5)
  float* base = partial + (size_t)sb * PLANE;
#pragma unroll
  for (int mi = 0; mi < 2; ++mi)
#pragma unroll
    for (int ni = 0; ni < 2; ++ni) {
      const f32x16 acc = accP[mi][ni] + accQ[mi][ni];
      const int col = wn * 64 + ni * 32 + r31;
#pragma unroll
      for (int reg = 0; reg < 16; ++reg) {
        const int rr  = (reg & 3) + 8 * (reg >> 2) + 4 * kg;
        const int row = row0 + wm * 64 + mi * 32 + rr;
        base[(size_t)row * NEXP + col] = acc[reg];
      }
    }
}

// ---------------- Gating: one wave per token; sums S partial planes ----------------
__global__ __launch_bounds__(256) void gate_kernel(const float* __restrict__ logits,
                                                   const float* __restrict__ bias,
                                                   float* __restrict__ out_w,
                                                   float* __restrict__ out_e, int S) {
    const int wave = threadIdx.x >> 6;
    const int lane = threadIdx.x & 63;
    const int t = blockIdx.x * 4 + wave;
    if (t >= T_TOK) return;

    float l4[4] = {0.f, 0.f, 0.f, 0.f};
    for (int s = 0; s < S; ++s) {  // fixed order -> deterministic
        const float4 v = *(const float4*)(&logits[(size_t)s * PLANE + (size_t)t * NEXP + lane * 4]);
        l4[0] += v.x; l4[1] += v.y; l4[2] += v.z; l4[3] += v.w;
    }
    const float4 bv = *(const float4*)(&bias[lane * 4]);

    float s4[4], c[4];
#pragma unroll
    for (int j = 0; j < 4; ++j) s4[j] = 1.f / (1.f + expf(-l4[j] * INV_S2));
    c[0] = s4[0] + bv.x;
    c[1] = s4[1] + bv.y;
    c[2] = s4[2] + bv.z;
    c[3] = s4[3] + bv.w;

    float a = fmaxf(c[0], c[1]), b = fminf(c[0], c[1]);
    float d = fmaxf(c[2], c[3]), e = fminf(c[2], c[3]);
    float m1 = fmaxf(a, d);
    float m2 = fmaxf(fminf(a, d), fmaxf(b, e));
#pragma unroll
    for (int off = 1; off < 8; off <<= 1) {
        const float o1 = __shfl_xor(m1, off);
        const float o2 = __shfl_xor(m2, off);
        const float n1 = fmaxf(m1, o1);
        const float n2 = fmaxf(fminf(m1, o1), fmaxf(m2, o2));
        m1 = n1; m2 = n2;
    }
    const float gs = m1 + m2;
    const int   g  = lane >> 3;

    int rank = 0;
#pragma unroll
    for (int gg = 0; gg < 8; ++gg) {
        const float og = __shfl(gs, gg * 8);
        rank += (og > gs) || (og == gs && gg < g);
    }
    const bool gsel = rank < 4;

    float v[4];
#pragma unroll
    for (int j = 0; j < 4; ++j) v[j] = gsel ? c[j] : 0.0f;

    float selw = 0.f;
    int   seli = 0;
    float wsum = 0.f;

#pragma unroll
    for (int k = 0; k < 8; ++k) {
        float bvv = v[0]; int bi = lane * 4; float br = s4[0];
#pragma unroll
        for (int j = 1; j < 4; ++j) {
            if (v[j] > bvv) { bvv = v[j]; bi = lane * 4 + j; br = s4[j]; }
        }
#pragma unroll
        for (int off = 32; off > 0; off >>= 1) {
            const float ov = __shfl_xor(bvv, off);
            const int   oi = __shfl_xor(bi, off);
            const float orr = __shfl_xor(br, off);
            if (ov > bvv || (ov == bvv && oi < bi)) { bvv = ov; bi = oi; br = orr; }
        }
        if (lane == k) { selw = br; seli = bi; }
        wsum += br;
        const int rem = bi - lane * 4;
#pragma unroll
        for (int j = 0; j < 4; ++j)
            if (rem == j) v[j] = -INFINITY;
    }

    if (lane < 8) {
        const float w = selw / (wsum + 1e-20f) * 2.5f;
        out_w[(size_t)t * 8 + lane] = w;
        out_e[(size_t)t * 8 + lane] = (float)seli;
    }
}

extern "C" void kernel_launch(void* const* d_in, const int* in_sizes, int n_in,
                              void* d_out, int out_size, void* d_ws, size_t ws_size,
                              hipStream_t stream) {
    const float* X    = (const float*)d_in[0];
    const float* W    = (const float*)d_in[1];
    const float* bias = (const float*)d_in[2];
    float* out = (float*)d_out;

    _Float16* img = (_Float16*)d_ws;
    const size_t woff = (size_t)NSTEP_TOT * BIMG_STEP;   // 7,340,032 B
    float* partial = (float*)((char*)d_ws + woff);

    int S = 1;
    if (ws_size >= woff + 4 * PLANE * sizeof(float)) S = 4;
    else if (ws_size >= woff + 2 * PLANE * sizeof(float)) S = 2;

    wconv<<<dim3(NSTEP_TOT * 2048 / 256), 256, 0, stream>>>(W, img);
    router_gemm<<<dim3((T_TOK / BM) * S), 512, 0, stream>>>(X, img, partial, S);
    gate_kernel<<<dim3(T_TOK / 4), 256, 0, stream>>>(partial, bias, out, out + (size_t)T_TOK * 8, S);
}